// Round 13
// baseline (236.951 us; speedup 1.0000x reference)
//
#include <hip/hip_runtime.h>
#include <hip/hip_bf16.h>

// LSTM cell fused kernel for MI355X (gfx950).
// B=65536, H=256. Packed GEMM [B,256]x[256,1024] bf16 MFMA + fused gates.
// R13: weights-in-VGPR. Wave owns one 16-j slice x 4 gates; its full weight
//      footprint (32 KB = 128 VGPRs as 32 x short8) is loaded ONCE and held
//      across 256 rows (4 double-buffered 64-row subtiles). Weight L2 traffic
//      512 MB -> 128 MB; weight VMEM instrs 524k -> 131k. K-loop = LDS+MFMA
//      only. launch_bounds(256,2): 2 blocks/CU alternate stage<->compute.

typedef __attribute__((ext_vector_type(8))) short short8;   // 8 bf16
typedef __attribute__((ext_vector_type(4))) float f32x4;

static constexpr int Bsz   = 65536;
static constexpr int Hdim  = 256;
static constexpr int RPB   = 256;                 // rows per block
static constexpr int NBLK  = (Bsz / RPB) * 4;     // 1024 blocks (4 j-quarters)

// float -> bf16 bits, round-to-nearest-even
__device__ __forceinline__ short f2bf(float f) {
    unsigned u = __float_as_uint(f);
    return (short)((u + 0x7FFFu + ((u >> 16) & 1u)) >> 16);
}
__device__ __forceinline__ float fast_rcp(float x) {
    float r;
    asm("v_rcp_f32 %0, %1" : "=v"(r) : "v"(x));
    return r;
}
__device__ __forceinline__ float sigm(float x) {
    return fast_rcp(1.0f + __expf(-x));
}
__device__ __forceinline__ float tanh_fast(float x) {
    return 2.0f * fast_rcp(1.0f + __expf(-2.0f * x)) - 1.0f;
}

// ---------------------------------------------------------------------------
// Pack Wf,Wc,Wi,Wo ([256,256] fp32) into bf16 B-fragment-major layout for
// mfma_f32_16x16x32_bf16 (verified R2..R12):
//   flat o = (((g*8 + ks)*16 + jf)*64 + lane)*8 + e
//   k = ks*32 + (lane>>4)*8 + e ;  j = jf*16 + (lane&15) ;  B[k][j] = W_g[j][k]
// ---------------------------------------------------------------------------
__global__ void __launch_bounds__(256)
prep_w_kernel(const float* __restrict__ Wf, const float* __restrict__ Wc,
              const float* __restrict__ Wi, const float* __restrict__ Wo,
              short* __restrict__ Bp)
{
    int o    = blockIdx.x * 256 + threadIdx.x;   // 0 .. 262143
    int e    = o & 7;
    int lane = (o >> 3) & 63;
    int jf   = (o >> 9) & 15;
    int ks   = (o >> 13) & 7;
    int g    = (o >> 16) & 3;
    int k = ks * 32 + (lane >> 4) * 8 + e;
    int j = jf * 16 + (lane & 15);
    const float* W = (g == 0) ? Wf : (g == 1) ? Wc : (g == 2) ? Wi : Wo;
    Bp[o] = f2bf(W[j * 256 + k]);
}

// ---------------------------------------------------------------------------
// Main. 1024 blocks x 256 threads (4 waves). Block = 256 rows x one j-quarter
// (64 gate-cols) x 4 gates. Wave w owns jf slice jq*4+w (16 j) for all rows.
// Weights live in 32 x short8 = 128 VGPRs per wave, loaded once.
// Rows processed as 4 subtiles of 64, double-buffered LDS, 1 barrier/iter.
// bid = 32a + 8q + b: rowtile = 8a + b (0..255), jq = q -> the 4 j-siblings
// of a rowtile share an XCD (combine L2 reuse + store-line merging in L2).
// ---------------------------------------------------------------------------
__global__ void __launch_bounds__(256, 2)
lstm_main(const float* __restrict__ inp, const float* __restrict__ hid,
          const float* __restrict__ cell, const short* __restrict__ Bp,
          const float* __restrict__ bfv, const float* __restrict__ bcv,
          const float* __restrict__ biv, const float* __restrict__ bov,
          float* __restrict__ out)
{
    __shared__ short As[2][64 * Hdim];   // 2 x 32 KB swizzled combine subtiles

    const int tid  = threadIdx.x;
    const int lane = tid & 63;
    const int wave = tid >> 6;           // 0..3
    const int lm   = lane & 15;
    const int lk   = lane >> 4;

    const int bid     = blockIdx.x;
    const int jq      = (bid >> 3) & 3;
    const int rowtile = (bid >> 5) * 8 + (bid & 7);   // 0..255
    const int rowblk  = rowtile * RPB;

    const int j         = jq * 64 + wave * 16 + lm;   // this lane's gate-col
    const int jf_global = jq * 4 + wave;              // j / 16

    // ---- one-time weight load: 32 x short8 = 128 VGPRs --------------------
    short8 wreg[32];                      // [ks*4+g], static-indexed after unroll
#pragma unroll
    for (int ks = 0; ks < 8; ++ks)
#pragma unroll
        for (int g = 0; g < 4; ++g) {
            int chunk = (g * 8 + ks) * 16 + jf_global;
            wreg[ks * 4 + g] = *reinterpret_cast<const short8*>(
                                   Bp + ((size_t)chunk * 64 + lane) * 8);
        }
    const float bF = bfv[j], bC = bcv[j], bI = biv[j], bO = bov[j];
    asm volatile("s_waitcnt vmcnt(0)" ::: "memory");
    __builtin_amdgcn_sched_barrier(0);   // pin: weights loaded once, up front

    float* out0 = out;                               // out gate
    float* out1 = out + (size_t)Bsz * Hdim;          // hidden_state
    float* out2 = out + (size_t)2 * Bsz * Hdim;      // cell_state

#pragma unroll 1
    for (int t = 0; t < 4; ++t) {
        const int buf = t & 1;
        const int r0  = rowblk + t * 64;

        // ---- stage subtile t: 64r x 256k, 2 rounds of 4 chunks ------------
#pragma unroll
        for (int round = 0; round < 2; ++round) {
            float4 Li[4][2], Lh[4][2];
#pragma unroll
            for (int c = 0; c < 4; ++c) {
                int cc  = tid + (round * 4 + c) * 256;    // chunk 0..2047
                int row = cc >> 5;                        // 0..63
                int k0  = (cc & 31) * 8;
                const float4* ip = reinterpret_cast<const float4*>(inp + (size_t)(r0 + row) * Hdim + k0);
                const float4* hp = reinterpret_cast<const float4*>(hid + (size_t)(r0 + row) * Hdim + k0);
                Li[c][0] = ip[0]; Li[c][1] = ip[1];
                Lh[c][0] = hp[0]; Lh[c][1] = hp[1];
            }
#pragma unroll
            for (int c = 0; c < 4; ++c) {
                int cc  = tid + (round * 4 + c) * 256;
                int row = cc >> 5;
                int k0  = (cc & 31) * 8;
                short8 v;
                v[0] = f2bf(Li[c][0].x + Lh[c][0].x);
                v[1] = f2bf(Li[c][0].y + Lh[c][0].y);
                v[2] = f2bf(Li[c][0].z + Lh[c][0].z);
                v[3] = f2bf(Li[c][0].w + Lh[c][0].w);
                v[4] = f2bf(Li[c][1].x + Lh[c][1].x);
                v[5] = f2bf(Li[c][1].y + Lh[c][1].y);
                v[6] = f2bf(Li[c][1].z + Lh[c][1].z);
                v[7] = f2bf(Li[c][1].w + Lh[c][1].w);
                int byte = (row * 512 + k0 * 2) ^ ((row & 7) << 4);
                *reinterpret_cast<short8*>(
                    reinterpret_cast<char*>(As[buf]) + byte) = v;
            }
        }

        __syncthreads();   // stage(t) visible; also orders K-loop(t-1) before
                           // any future re-stage of this buffer (see header)

        // ---- acc init = bias ---------------------------------------------
        f32x4 acc[4][4];                 // [gate][mf] = 64 VGPRs
        acc[0][0] = (f32x4){bF, bF, bF, bF};
        acc[1][0] = (f32x4){bC, bC, bC, bC};
        acc[2][0] = (f32x4){bI, bI, bI, bI};
        acc[3][0] = (f32x4){bO, bO, bO, bO};
#pragma unroll
        for (int g = 0; g < 4; ++g)
#pragma unroll
            for (int mf = 1; mf < 4; ++mf)
                acc[g][mf] = acc[g][0];

        // ---- K-loop: LDS + register weights only -------------------------
        const char* A = reinterpret_cast<const char*>(As[buf]);
#pragma unroll
        for (int ks = 0; ks < 8; ++ks) {
            short8 cf[4];
#pragma unroll
            for (int mf = 0; mf < 4; ++mf) {
                int row  = mf * 16 + lm;
                int byte = (row * 512 + (ks * 32 + lk * 8) * 2) ^ ((row & 7) << 4);
                cf[mf] = *reinterpret_cast<const short8*>(A + byte);
            }
#pragma unroll
            for (int g = 0; g < 4; ++g) {
                const short8 b = wreg[ks * 4 + g];
                acc[g][0] = __builtin_amdgcn_mfma_f32_16x16x32_bf16(cf[0], b, acc[g][0], 0, 0, 0);
                acc[g][1] = __builtin_amdgcn_mfma_f32_16x16x32_bf16(cf[1], b, acc[g][1], 0, 0, 0);
                acc[g][2] = __builtin_amdgcn_mfma_f32_16x16x32_bf16(cf[2], b, acc[g][2], 0, 0, 0);
                acc[g][3] = __builtin_amdgcn_mfma_f32_16x16x32_bf16(cf[3], b, acc[g][3], 0, 0, 0);
            }
        }

        // ---- epilogue for these 64 rows ----------------------------------
#pragma unroll
        for (int mf = 0; mf < 4; ++mf) {
            float cv[4];
#pragma unroll
            for (int r = 0; r < 4; ++r)
                cv[r] = cell[(size_t)(r0 + mf * 16 + lk * 4 + r) * Hdim + j];
#pragma unroll
            for (int r = 0; r < 4; ++r) {
                int row = r0 + mf * 16 + lk * 4 + r;   // C/D: row=(lane>>4)*4+reg
                size_t off = (size_t)row * Hdim + j;
                float F = sigm(acc[0][mf][r]);
                float C = tanh_fast(acc[1][mf][r]);
                float I = sigm(sigm(acc[2][mf][r]));   // double sigmoid, per ref
                float O = sigm(acc[3][mf][r]);
                float cs = cv[r] * F + C * I;
                float hs = O * tanh_fast(cs);
                out0[off] = O;
                out1[off] = hs;
                out2[off] = cs;
            }
        }
    }
}

extern "C" void kernel_launch(void* const* d_in, const int* in_sizes, int n_in,
                              void* d_out, int out_size, void* d_ws, size_t ws_size,
                              hipStream_t stream)
{
    const float* inp  = (const float*)d_in[0];
    const float* hid  = (const float*)d_in[1];
    const float* cell = (const float*)d_in[2];
    const float* Wf   = (const float*)d_in[3];
    const float* bf_  = (const float*)d_in[4];
    const float* Wc   = (const float*)d_in[5];
    const float* bc_  = (const float*)d_in[6];
    const float* Wi   = (const float*)d_in[7];
    const float* bi_  = (const float*)d_in[8];
    const float* Wo   = (const float*)d_in[9];
    const float* bo_  = (const float*)d_in[10];

    short* Bp = (short*)d_ws;    // 512 KB packed bf16 weights

    prep_w_kernel<<<1024, 256, 0, stream>>>(Wf, Wc, Wi, Wo, Bp);
    lstm_main<<<NBLK, 256, 0, stream>>>(inp, hid, cell, Bp,
                                        bf_, bc_, bi_, bo_, (float*)d_out);
}

// Round 14
// 129.763 us; speedup vs baseline: 1.8260x; 1.8260x over previous
//
#include <hip/hip_runtime.h>
#include <hip/hip_bf16.h>

// LSTM cell fused kernel for MI355X (gfx950).
// B=65536, H=256. Packed GEMM [B,256]x[256,1024] bf16 MFMA + fused gates.
// R14: R12 weight amortization (TROWS=64/wave, acc[4][4]) + R5 concurrency
//      (4-wave 256-thr blocks on j-quarters -> 4 independent blocks/CU).
//      Weight traffic stays 512 MB; staging x4 (L2-absorbed, XCD-paired).

typedef __attribute__((ext_vector_type(8))) short short8;   // 8 bf16
typedef __attribute__((ext_vector_type(4))) float f32x4;

static constexpr int Bsz   = 65536;
static constexpr int Hdim  = 256;
static constexpr int TROWS = 64;
static constexpr int NBLK  = (Bsz / TROWS) * 4;   // 4096 blocks (4 j-quarters)

// float -> bf16 bits, round-to-nearest-even
__device__ __forceinline__ short f2bf(float f) {
    unsigned u = __float_as_uint(f);
    return (short)((u + 0x7FFFu + ((u >> 16) & 1u)) >> 16);
}
__device__ __forceinline__ float fast_rcp(float x) {
    float r;
    asm("v_rcp_f32 %0, %1" : "=v"(r) : "v"(x));
    return r;
}
__device__ __forceinline__ float sigm(float x) {
    return fast_rcp(1.0f + __expf(-x));
}
__device__ __forceinline__ float tanh_fast(float x) {
    return 2.0f * fast_rcp(1.0f + __expf(-2.0f * x)) - 1.0f;
}

// ---------------------------------------------------------------------------
// Pack Wf,Wc,Wi,Wo ([256,256] fp32) into bf16 B-fragment-major layout for
// mfma_f32_16x16x32_bf16 (verified R2..R13):
//   flat o = (((g*8 + ks)*16 + jf)*64 + lane)*8 + e
//   k = ks*32 + (lane>>4)*8 + e ;  j = jf*16 + (lane&15) ;  B[k][j] = W_g[j][k]
// ---------------------------------------------------------------------------
__global__ void __launch_bounds__(256)
prep_w_kernel(const float* __restrict__ Wf, const float* __restrict__ Wc,
              const float* __restrict__ Wi, const float* __restrict__ Wo,
              short* __restrict__ Bp)
{
    int o    = blockIdx.x * 256 + threadIdx.x;   // 0 .. 262143
    int e    = o & 7;
    int lane = (o >> 3) & 63;
    int jf   = (o >> 9) & 15;
    int ks   = (o >> 13) & 7;
    int g    = (o >> 16) & 3;
    int k = ks * 32 + (lane >> 4) * 8 + e;
    int j = jf * 16 + (lane & 15);
    const float* W = (g == 0) ? Wf : (g == 1) ? Wc : (g == 2) ? Wi : Wo;
    Bp[o] = f2bf(W[j * 256 + k]);
}

// ---------------------------------------------------------------------------
// Main. 4096 blocks x 256 threads (4 waves). Block = 64 rows x one j-quarter
// (64 gate-cols) x 4 gates. Wave w owns jf slice jq*4+w (16 j) for all
// 64 rows -> acc[4][4] = 64 VGPRs; weight fragments unique per wave.
// bid = 32a + 8q + b: rowtile = 8a + b (0..1023), jq = q -> the 4 j-siblings
// of a rowtile share an XCD (combine staged 4x but L2-hit after first;
// store lines merge in L2).
// ---------------------------------------------------------------------------
__global__ void __launch_bounds__(256, 4)
lstm_main(const float* __restrict__ inp, const float* __restrict__ hid,
          const float* __restrict__ cell, const short* __restrict__ Bp,
          const float* __restrict__ bfv, const float* __restrict__ bcv,
          const float* __restrict__ biv, const float* __restrict__ bov,
          float* __restrict__ out)
{
    __shared__ short As[TROWS * Hdim];   // 32 KB swizzled combine tile

    const int tid  = threadIdx.x;
    const int lane = tid & 63;
    const int wave = tid >> 6;           // 0..3
    const int lm   = lane & 15;
    const int lk   = lane >> 4;

    const int bid     = blockIdx.x;
    const int jq      = (bid >> 3) & 3;
    const int rowtile = (bid >> 5) * 8 + (bid & 7);   // 0..1023
    const int rowblk  = rowtile * TROWS;

    const int j         = jq * 64 + wave * 16 + lm;   // this lane's gate-col
    const int jf_global = jq * 4 + wave;              // j / 16

    // ---- stage combine = input + hidden (bf16) into LDS, XOR-swizzled -----
    // 2048 16B-chunks; 256 threads x 8 chunks, in 4 rounds of 2 (reg cap).
#pragma unroll
    for (int round = 0; round < 4; ++round) {
        float4 Li[2][2], Lh[2][2];
#pragma unroll
        for (int c = 0; c < 2; ++c) {
            int cc  = tid + (round * 2 + c) * 256;    // chunk 0..2047
            int row = cc >> 5;                        // 0..63
            int k0  = (cc & 31) * 8;                  // 0..248
            const float4* ip = reinterpret_cast<const float4*>(inp + (size_t)(rowblk + row) * Hdim + k0);
            const float4* hp = reinterpret_cast<const float4*>(hid + (size_t)(rowblk + row) * Hdim + k0);
            Li[c][0] = ip[0]; Li[c][1] = ip[1];
            Lh[c][0] = hp[0]; Lh[c][1] = hp[1];
        }
#pragma unroll
        for (int c = 0; c < 2; ++c) {
            int cc  = tid + (round * 2 + c) * 256;
            int row = cc >> 5;
            int k0  = (cc & 31) * 8;
            short8 v;
            v[0] = f2bf(Li[c][0].x + Lh[c][0].x);
            v[1] = f2bf(Li[c][0].y + Lh[c][0].y);
            v[2] = f2bf(Li[c][0].z + Lh[c][0].z);
            v[3] = f2bf(Li[c][0].w + Lh[c][0].w);
            v[4] = f2bf(Li[c][1].x + Lh[c][1].x);
            v[5] = f2bf(Li[c][1].y + Lh[c][1].y);
            v[6] = f2bf(Li[c][1].z + Lh[c][1].z);
            v[7] = f2bf(Li[c][1].w + Lh[c][1].w);
            int byte = (row * 512 + k0 * 2) ^ ((row & 7) << 4);
            *reinterpret_cast<short8*>(reinterpret_cast<char*>(As) + byte) = v;
        }
    }

    // bias per lane (j fixed) — only 4 regs live through the GEMM
    const float bF = bfv[j], bC = bcv[j], bI = biv[j], bO = bov[j];

    __syncthreads();                     // As visible

    // ---- acc init = bias --------------------------------------------------
    f32x4 acc[4][4];                     // [gate][mf] = 64 VGPRs
    acc[0][0] = (f32x4){bF, bF, bF, bF};
    acc[1][0] = (f32x4){bC, bC, bC, bC};
    acc[2][0] = (f32x4){bI, bI, bI, bI};
    acc[3][0] = (f32x4){bO, bO, bO, bO};
#pragma unroll
    for (int g = 0; g < 4; ++g)
#pragma unroll
        for (int mf = 1; mf < 4; ++mf)
            acc[g][mf] = acc[g][0];

    // ---- GEMM: K=256 in 8 steps; 4 ds_read + 4 weight loads + 16 MFMA -----
    const char* A = reinterpret_cast<const char*>(As);
#pragma unroll
    for (int ks = 0; ks < 8; ++ks) {
        short8 cf[4];
#pragma unroll
        for (int mf = 0; mf < 4; ++mf) {
            int row  = mf * 16 + lm;
            int byte = (row * 512 + (ks * 32 + lk * 8) * 2) ^ ((row & 7) << 4);
            cf[mf] = *reinterpret_cast<const short8*>(A + byte);
        }
#pragma unroll
        for (int g = 0; g < 4; ++g) {
            int chunk = (g * 8 + ks) * 16 + jf_global;
            short8 b = *reinterpret_cast<const short8*>(
                           Bp + ((size_t)chunk * 64 + lane) * 8);   // 1KB, contig
            acc[g][0] = __builtin_amdgcn_mfma_f32_16x16x32_bf16(cf[0], b, acc[g][0], 0, 0, 0);
            acc[g][1] = __builtin_amdgcn_mfma_f32_16x16x32_bf16(cf[1], b, acc[g][1], 0, 0, 0);
            acc[g][2] = __builtin_amdgcn_mfma_f32_16x16x32_bf16(cf[2], b, acc[g][2], 0, 0, 0);
            acc[g][3] = __builtin_amdgcn_mfma_f32_16x16x32_bf16(cf[3], b, acc[g][3], 0, 0, 0);
        }
    }

    // ---- cell loads AFTER GEMM (not live through K-loop) ------------------
    float* out0 = out;                               // out gate
    float* out1 = out + (size_t)Bsz * Hdim;          // hidden_state
    float* out2 = out + (size_t)2 * Bsz * Hdim;      // cell_state

#pragma unroll
    for (int mf = 0; mf < 4; ++mf) {
        float cv[4];
#pragma unroll
        for (int r = 0; r < 4; ++r)
            cv[r] = cell[(size_t)(rowblk + mf * 16 + lk * 4 + r) * Hdim + j];
#pragma unroll
        for (int r = 0; r < 4; ++r) {
            int row = rowblk + mf * 16 + lk * 4 + r;   // C/D: row=(lane>>4)*4+reg
            size_t off = (size_t)row * Hdim + j;
            float F = sigm(acc[0][mf][r]);
            float C = tanh_fast(acc[1][mf][r]);
            float I = sigm(sigm(acc[2][mf][r]));       // double sigmoid, per ref
            float O = sigm(acc[3][mf][r]);
            float cs = cv[r] * F + C * I;
            float hs = O * tanh_fast(cs);
            out0[off] = O;
            out1[off] = hs;
            out2[off] = cs;
        }
    }
}

extern "C" void kernel_launch(void* const* d_in, const int* in_sizes, int n_in,
                              void* d_out, int out_size, void* d_ws, size_t ws_size,
                              hipStream_t stream)
{
    const float* inp  = (const float*)d_in[0];
    const float* hid  = (const float*)d_in[1];
    const float* cell = (const float*)d_in[2];
    const float* Wf   = (const float*)d_in[3];
    const float* bf_  = (const float*)d_in[4];
    const float* Wc   = (const float*)d_in[5];
    const float* bc_  = (const float*)d_in[6];
    const float* Wi   = (const float*)d_in[7];
    const float* bi_  = (const float*)d_in[8];
    const float* Wo   = (const float*)d_in[9];
    const float* bo_  = (const float*)d_in[10];

    short* Bp = (short*)d_ws;    // 512 KB packed bf16 weights

    prep_w_kernel<<<1024, 256, 0, stream>>>(Wf, Wc, Wi, Wo, Bp);
    lstm_main<<<NBLK, 256, 0, stream>>>(inp, hid, cell, Bp,
                                        bf_, bc_, bi_, bo_, (float*)d_out);
}

// Round 15
// 129.601 us; speedup vs baseline: 1.8283x; 1.0012x over previous
//
#include <hip/hip_runtime.h>
#include <hip/hip_bf16.h>

// LSTM cell fused kernel for MI355X (gfx950).
// B=65536, H=256. Packed GEMM [B,256]x[256,1024] bf16 MFMA + fused gates.
// R15: R12 base (verified best, 116.8us) + TA-lean epilogue. After the K-loop
//      the As tile is dead -> per-wave LDS scratch (stride 20 floats, 16B-
//      aligned rows). Cell loaded as 4x dwordx4 (transposed-coalesced) and
//      LDS-transposed to native; outputs written native->scratch->transposed
//      dwordx4 stores. Per-thread VMEM 116 -> 68 instrs.

typedef __attribute__((ext_vector_type(8))) short short8;   // 8 bf16
typedef __attribute__((ext_vector_type(4))) float f32x4;

static constexpr int Bsz   = 65536;
static constexpr int Hdim  = 256;
static constexpr int TROWS = 64;
static constexpr int NBLK  = (Bsz / TROWS) * 2;   // 2048 blocks (2 j-halves)
static constexpr int SCRW  = 20;                  // scratch row stride (floats)

// float -> bf16 bits, round-to-nearest-even
__device__ __forceinline__ short f2bf(float f) {
    unsigned u = __float_as_uint(f);
    return (short)((u + 0x7FFFu + ((u >> 16) & 1u)) >> 16);
}
__device__ __forceinline__ float fast_rcp(float x) {
    float r;
    asm("v_rcp_f32 %0, %1" : "=v"(r) : "v"(x));
    return r;
}
__device__ __forceinline__ float sigm(float x) {
    return fast_rcp(1.0f + __expf(-x));
}
__device__ __forceinline__ float tanh_fast(float x) {
    return 2.0f * fast_rcp(1.0f + __expf(-2.0f * x)) - 1.0f;
}
__device__ __forceinline__ void lds_fence() {
    asm volatile("s_waitcnt lgkmcnt(0)" ::: "memory");
    __builtin_amdgcn_sched_barrier(0);
}

// ---------------------------------------------------------------------------
// Pack Wf,Wc,Wi,Wo ([256,256] fp32) into bf16 B-fragment-major layout for
// mfma_f32_16x16x32_bf16 (verified R2..R14):
//   flat o = (((g*8 + ks)*16 + jf)*64 + lane)*8 + e
//   k = ks*32 + (lane>>4)*8 + e ;  j = jf*16 + (lane&15) ;  B[k][j] = W_g[j][k]
// ---------------------------------------------------------------------------
__global__ void __launch_bounds__(256)
prep_w_kernel(const float* __restrict__ Wf, const float* __restrict__ Wc,
              const float* __restrict__ Wi, const float* __restrict__ Wo,
              short* __restrict__ Bp)
{
    int o    = blockIdx.x * 256 + threadIdx.x;   // 0 .. 262143
    int e    = o & 7;
    int lane = (o >> 3) & 63;
    int jf   = (o >> 9) & 15;
    int ks   = (o >> 13) & 7;
    int g    = (o >> 16) & 3;
    int k = ks * 32 + (lane >> 4) * 8 + e;
    int j = jf * 16 + (lane & 15);
    const float* W = (g == 0) ? Wf : (g == 1) ? Wc : (g == 2) ? Wi : Wo;
    Bp[o] = f2bf(W[j * 256 + k]);
}

// ---------------------------------------------------------------------------
// Main. 2048 blocks x 512 threads (8 waves). Block = 64 rows x 128 gate-cols
// (one j-half) x 4 gates. Wave w owns j in [jh*128 + w*16, +16) for ALL
// 64 rows -> acc[4][4] = 64 VGPRs; weight fragments unique per wave & block.
// bid = 16a + 8h + b: rowtile = 8a + b, jh = h -> the 2 j-siblings of a
// rowtile share an XCD (combine L2 reuse + store-line merging in L2).
// ---------------------------------------------------------------------------
__global__ void __launch_bounds__(512, 4)
lstm_main(const float* __restrict__ inp, const float* __restrict__ hid,
          const float* __restrict__ cell, const short* __restrict__ Bp,
          const float* __restrict__ bfv, const float* __restrict__ bcv,
          const float* __restrict__ biv, const float* __restrict__ bov,
          float* __restrict__ out)
{
    __shared__ short As[TROWS * Hdim];   // 32 KB swizzled combine tile / scratch

    const int tid  = threadIdx.x;
    const int lane = tid & 63;
    const int wave = tid >> 6;           // 0..7
    const int lm   = lane & 15;
    const int lk   = lane >> 4;

    const int bid     = blockIdx.x;
    const int rowtile = (bid >> 4) * 8 + (bid & 7);   // 0..1023
    const int jh      = (bid >> 3) & 1;
    const int rowblk  = rowtile * TROWS;

    const int j         = jh * 128 + wave * 16 + lm;  // this lane's gate-col
    const int jf_global = jh * 8 + wave;              // j / 16

    // epilogue transpose coords
    const int rT    = lane >> 2;                      // 0..15
    const int jc    = (lane & 3) * 4;                 // 0,4,8,12 (within 16-j slice)
    const int jcol4 = jh * 128 + wave * 16 + jc;      // float4 col base

    // ---- stage combine = input + hidden (bf16) into LDS, XOR-swizzled -----
    // 2048 16B-chunks; 512 threads x 4 chunks, in 2 rounds of 2 (reg cap).
#pragma unroll
    for (int round = 0; round < 2; ++round) {
        float4 Li[2][2], Lh[2][2];
#pragma unroll
        for (int c = 0; c < 2; ++c) {
            int cc  = tid + (round * 2 + c) * 512;    // chunk 0..2047
            int row = cc >> 5;                        // 0..63
            int k0  = (cc & 31) * 8;                  // 0..248
            const float4* ip = reinterpret_cast<const float4*>(inp + (size_t)(rowblk + row) * Hdim + k0);
            const float4* hp = reinterpret_cast<const float4*>(hid + (size_t)(rowblk + row) * Hdim + k0);
            Li[c][0] = ip[0]; Li[c][1] = ip[1];
            Lh[c][0] = hp[0]; Lh[c][1] = hp[1];
        }
#pragma unroll
        for (int c = 0; c < 2; ++c) {
            int cc  = tid + (round * 2 + c) * 512;
            int row = cc >> 5;
            int k0  = (cc & 31) * 8;
            short8 v;
            v[0] = f2bf(Li[c][0].x + Lh[c][0].x);
            v[1] = f2bf(Li[c][0].y + Lh[c][0].y);
            v[2] = f2bf(Li[c][0].z + Lh[c][0].z);
            v[3] = f2bf(Li[c][0].w + Lh[c][0].w);
            v[4] = f2bf(Li[c][1].x + Lh[c][1].x);
            v[5] = f2bf(Li[c][1].y + Lh[c][1].y);
            v[6] = f2bf(Li[c][1].z + Lh[c][1].z);
            v[7] = f2bf(Li[c][1].w + Lh[c][1].w);
            int byte = (row * 512 + k0 * 2) ^ ((row & 7) << 4);
            *reinterpret_cast<short8*>(reinterpret_cast<char*>(As) + byte) = v;
        }
    }

    // bias per lane (j fixed) — only 4 regs live through the GEMM
    const float bF = bfv[j], bC = bcv[j], bI = biv[j], bO = bov[j];

    __syncthreads();                     // As visible

    // ---- acc init = bias --------------------------------------------------
    f32x4 acc[4][4];                     // [gate][mf] = 64 VGPRs
    acc[0][0] = (f32x4){bF, bF, bF, bF};
    acc[1][0] = (f32x4){bC, bC, bC, bC};
    acc[2][0] = (f32x4){bI, bI, bI, bI};
    acc[3][0] = (f32x4){bO, bO, bO, bO};
#pragma unroll
    for (int g = 0; g < 4; ++g)
#pragma unroll
        for (int mf = 1; mf < 4; ++mf)
            acc[g][mf] = acc[g][0];

    // ---- GEMM: K=256 in 8 steps; 4 ds_read + 4 weight loads + 16 MFMA -----
    const char* A = reinterpret_cast<const char*>(As);
#pragma unroll
    for (int ks = 0; ks < 8; ++ks) {
        short8 cf[4];
#pragma unroll
        for (int mf = 0; mf < 4; ++mf) {
            int row  = mf * 16 + lm;
            int byte = (row * 512 + (ks * 32 + lk * 8) * 2) ^ ((row & 7) << 4);
            cf[mf] = *reinterpret_cast<const short8*>(A + byte);
        }
#pragma unroll
        for (int g = 0; g < 4; ++g) {
            int chunk = (g * 8 + ks) * 16 + jf_global;
            short8 b = *reinterpret_cast<const short8*>(
                           Bp + ((size_t)chunk * 64 + lane) * 8);   // 1KB, contig
            acc[g][0] = __builtin_amdgcn_mfma_f32_16x16x32_bf16(cf[0], b, acc[g][0], 0, 0, 0);
            acc[g][1] = __builtin_amdgcn_mfma_f32_16x16x32_bf16(cf[1], b, acc[g][1], 0, 0, 0);
            acc[g][2] = __builtin_amdgcn_mfma_f32_16x16x32_bf16(cf[2], b, acc[g][2], 0, 0, 0);
            acc[g][3] = __builtin_amdgcn_mfma_f32_16x16x32_bf16(cf[3], b, acc[g][3], 0, 0, 0);
        }
    }

    // ---- cell loads: 4 x dwordx4, transposed-coalesced (issued pre-barrier)
    float4 cl[2][2];                      // [pass][i]
#pragma unroll
    for (int p = 0; p < 2; ++p)
#pragma unroll
        for (int i = 0; i < 2; ++i) {
            int row = rowblk + p * 32 + rT + i * 16;
            cl[p][i] = *reinterpret_cast<const float4*>(
                           cell + (size_t)row * Hdim + jcol4);
        }

    __syncthreads();                      // all waves done reading As

    // ---- TA-lean epilogue: per-wave scratch transpose ---------------------
    float* scr = reinterpret_cast<float*>(As) + wave * (32 * SCRW);

    float* out0 = out;                               // out gate
    float* out1 = out + (size_t)Bsz * Hdim;          // hidden_state
    float* out2 = out + (size_t)2 * Bsz * Hdim;      // cell_state

#pragma unroll
    for (int p = 0; p < 2; ++p) {
        lds_fence();                      // prior scratch reads complete
        // cell -> scratch (transposed layout in, native layout out)
#pragma unroll
        for (int i = 0; i < 2; ++i)
            *reinterpret_cast<float4*>(&scr[(rT + i * 16) * SCRW + jc]) = cl[p][i];
        lds_fence();

        // native reads + gate math for rows p*32 .. p*32+31
        float o_[2][4], h_[2][4], c_[2][4];
#pragma unroll
        for (int m = 0; m < 2; ++m) {
            const int mf = p * 2 + m;
#pragma unroll
            for (int r = 0; r < 4; ++r) {
                float cv = scr[(m * 16 + lk * 4 + r) * SCRW + lm];
                float F = sigm(acc[0][mf][r]);
                float C = tanh_fast(acc[1][mf][r]);
                float I = sigm(sigm(acc[2][mf][r]));   // double sigmoid, per ref
                float O = sigm(acc[3][mf][r]);
                float cs = cv * F + C * I;
                o_[m][r] = O;
                h_[m][r] = O * tanh_fast(cs);
                c_[m][r] = cs;
            }
        }

        // three arrays: native scatter -> transposed dwordx4 gather + store
#pragma unroll
        for (int x = 0; x < 3; ++x) {
            lds_fence();                  // prior reads complete before overwrite
#pragma unroll
            for (int m = 0; m < 2; ++m)
#pragma unroll
                for (int r = 0; r < 4; ++r) {
                    float v = (x == 0) ? o_[m][r] : (x == 1) ? h_[m][r] : c_[m][r];
                    scr[(m * 16 + lk * 4 + r) * SCRW + lm] = v;
                }
            lds_fence();
            float* op = (x == 0) ? out0 : (x == 1) ? out1 : out2;
#pragma unroll
            for (int i = 0; i < 2; ++i) {
                int rl  = rT + i * 16;
                int row = rowblk + p * 32 + rl;
                float4 t = *reinterpret_cast<const float4*>(&scr[rl * SCRW + jc]);
                *reinterpret_cast<float4*>(op + (size_t)row * Hdim + jcol4) = t;
            }
        }
    }
}

extern "C" void kernel_launch(void* const* d_in, const int* in_sizes, int n_in,
                              void* d_out, int out_size, void* d_ws, size_t ws_size,
                              hipStream_t stream)
{
    const float* inp  = (const float*)d_in[0];
    const float* hid  = (const float*)d_in[1];
    const float* cell = (const float*)d_in[2];
    const float* Wf   = (const float*)d_in[3];
    const float* bf_  = (const float*)d_in[4];
    const float* Wc   = (const float*)d_in[5];
    const float* bc_  = (const float*)d_in[6];
    const float* Wi   = (const float*)d_in[7];
    const float* bi_  = (const float*)d_in[8];
    const float* Wo   = (const float*)d_in[9];
    const float* bo_  = (const float*)d_in[10];

    short* Bp = (short*)d_ws;    // 512 KB packed bf16 weights

    prep_w_kernel<<<1024, 256, 0, stream>>>(Wf, Wc, Wi, Wo, Bp);
    lstm_main<<<NBLK, 512, 0, stream>>>(inp, hid, cell, Bp,
                                        bf_, bc_, bi_, bo_, (float*)d_out);
}

// Round 16
// 115.613 us; speedup vs baseline: 2.0495x; 1.1210x over previous
//
#include <hip/hip_runtime.h>
#include <hip/hip_bf16.h>

// LSTM cell fused kernel for MI355X (gfx950).
// B=65536, H=256. Packed GEMM [B,256]x[256,1024] bf16 MFMA + fused gates.
// R16 = R12 verbatim (verified best: 116.8us, clean counters).
//      TROWS=64 weight amortization: 2048 blocks x 512 thr (8 waves); block =
//      64 rows x 128 j-half; wave = 64r x 16j x 4 gates (acc[4][4]=64).
//      Every weight fragment loaded once per block. Staging in 2 rounds of 2
//      chunks, cell loaded AFTER GEMM, bias pre-barrier, scalar stores.

typedef __attribute__((ext_vector_type(8))) short short8;   // 8 bf16
typedef __attribute__((ext_vector_type(4))) float f32x4;

static constexpr int Bsz   = 65536;
static constexpr int Hdim  = 256;
static constexpr int TROWS = 64;
static constexpr int NBLK  = (Bsz / TROWS) * 2;   // 2048 blocks (2 j-halves)

// float -> bf16 bits, round-to-nearest-even
__device__ __forceinline__ short f2bf(float f) {
    unsigned u = __float_as_uint(f);
    return (short)((u + 0x7FFFu + ((u >> 16) & 1u)) >> 16);
}
__device__ __forceinline__ float fast_rcp(float x) {
    float r;
    asm("v_rcp_f32 %0, %1" : "=v"(r) : "v"(x));
    return r;
}
__device__ __forceinline__ float sigm(float x) {
    return fast_rcp(1.0f + __expf(-x));
}
__device__ __forceinline__ float tanh_fast(float x) {
    return 2.0f * fast_rcp(1.0f + __expf(-2.0f * x)) - 1.0f;
}

// ---------------------------------------------------------------------------
// Pack Wf,Wc,Wi,Wo ([256,256] fp32) into bf16 B-fragment-major layout for
// mfma_f32_16x16x32_bf16 (verified R2..R15):
//   flat o = (((g*8 + ks)*16 + jf)*64 + lane)*8 + e
//   k = ks*32 + (lane>>4)*8 + e ;  j = jf*16 + (lane&15) ;  B[k][j] = W_g[j][k]
// ---------------------------------------------------------------------------
__global__ void __launch_bounds__(256)
prep_w_kernel(const float* __restrict__ Wf, const float* __restrict__ Wc,
              const float* __restrict__ Wi, const float* __restrict__ Wo,
              short* __restrict__ Bp)
{
    int o    = blockIdx.x * 256 + threadIdx.x;   // 0 .. 262143
    int e    = o & 7;
    int lane = (o >> 3) & 63;
    int jf   = (o >> 9) & 15;
    int ks   = (o >> 13) & 7;
    int g    = (o >> 16) & 3;
    int k = ks * 32 + (lane >> 4) * 8 + e;
    int j = jf * 16 + (lane & 15);
    const float* W = (g == 0) ? Wf : (g == 1) ? Wc : (g == 2) ? Wi : Wo;
    Bp[o] = f2bf(W[j * 256 + k]);
}

// ---------------------------------------------------------------------------
// Main. 2048 blocks x 512 threads (8 waves). Block = 64 rows x 128 gate-cols
// (one j-half) x 4 gates. Wave w owns j in [jh*128 + w*16, +16) for ALL
// 64 rows -> acc[4][4] = 64 VGPRs; weight fragments unique per wave & block.
// bid = 16a + 8h + b: rowtile = 8a + b, jh = h -> the 2 j-siblings of a
// rowtile share an XCD (combine L2 reuse + store-line merging in L2).
// ---------------------------------------------------------------------------
__global__ void __launch_bounds__(512, 4)
lstm_main(const float* __restrict__ inp, const float* __restrict__ hid,
          const float* __restrict__ cell, const short* __restrict__ Bp,
          const float* __restrict__ bfv, const float* __restrict__ bcv,
          const float* __restrict__ biv, const float* __restrict__ bov,
          float* __restrict__ out)
{
    __shared__ short As[TROWS * Hdim];   // 32 KB swizzled combine tile

    const int tid  = threadIdx.x;
    const int lane = tid & 63;
    const int wave = tid >> 6;           // 0..7
    const int lm   = lane & 15;
    const int lk   = lane >> 4;

    const int bid     = blockIdx.x;
    const int rowtile = (bid >> 4) * 8 + (bid & 7);   // 0..1023
    const int jh      = (bid >> 3) & 1;
    const int rowblk  = rowtile * TROWS;

    const int j         = jh * 128 + wave * 16 + lm;  // this lane's gate-col
    const int jf_global = jh * 8 + wave;              // j / 16

    // ---- stage combine = input + hidden (bf16) into LDS, XOR-swizzled -----
    // 2048 16B-chunks; 512 threads x 4 chunks, in 2 rounds of 2 (reg cap).
#pragma unroll
    for (int round = 0; round < 2; ++round) {
        float4 Li[2][2], Lh[2][2];
#pragma unroll
        for (int c = 0; c < 2; ++c) {
            int cc  = tid + (round * 2 + c) * 512;    // chunk 0..2047
            int row = cc >> 5;                        // 0..63
            int k0  = (cc & 31) * 8;                  // 0..248
            const float4* ip = reinterpret_cast<const float4*>(inp + (size_t)(rowblk + row) * Hdim + k0);
            const float4* hp = reinterpret_cast<const float4*>(hid + (size_t)(rowblk + row) * Hdim + k0);
            Li[c][0] = ip[0]; Li[c][1] = ip[1];
            Lh[c][0] = hp[0]; Lh[c][1] = hp[1];
        }
#pragma unroll
        for (int c = 0; c < 2; ++c) {
            int cc  = tid + (round * 2 + c) * 512;
            int row = cc >> 5;
            int k0  = (cc & 31) * 8;
            short8 v;
            v[0] = f2bf(Li[c][0].x + Lh[c][0].x);
            v[1] = f2bf(Li[c][0].y + Lh[c][0].y);
            v[2] = f2bf(Li[c][0].z + Lh[c][0].z);
            v[3] = f2bf(Li[c][0].w + Lh[c][0].w);
            v[4] = f2bf(Li[c][1].x + Lh[c][1].x);
            v[5] = f2bf(Li[c][1].y + Lh[c][1].y);
            v[6] = f2bf(Li[c][1].z + Lh[c][1].z);
            v[7] = f2bf(Li[c][1].w + Lh[c][1].w);
            int byte = (row * 512 + k0 * 2) ^ ((row & 7) << 4);
            *reinterpret_cast<short8*>(reinterpret_cast<char*>(As) + byte) = v;
        }
    }

    // bias per lane (j fixed) — only 4 regs live through the GEMM
    const float bF = bfv[j], bC = bcv[j], bI = biv[j], bO = bov[j];

    __syncthreads();                     // As visible

    // ---- acc init = bias --------------------------------------------------
    f32x4 acc[4][4];                     // [gate][mf] = 64 VGPRs
    acc[0][0] = (f32x4){bF, bF, bF, bF};
    acc[1][0] = (f32x4){bC, bC, bC, bC};
    acc[2][0] = (f32x4){bI, bI, bI, bI};
    acc[3][0] = (f32x4){bO, bO, bO, bO};
#pragma unroll
    for (int g = 0; g < 4; ++g)
#pragma unroll
        for (int mf = 1; mf < 4; ++mf)
            acc[g][mf] = acc[g][0];

    // ---- GEMM: K=256 in 8 steps; 4 ds_read + 4 weight loads + 16 MFMA -----
    const char* A = reinterpret_cast<const char*>(As);
#pragma unroll
    for (int ks = 0; ks < 8; ++ks) {
        short8 cf[4];
#pragma unroll
        for (int mf = 0; mf < 4; ++mf) {
            int row  = mf * 16 + lm;
            int byte = (row * 512 + (ks * 32 + lk * 8) * 2) ^ ((row & 7) << 4);
            cf[mf] = *reinterpret_cast<const short8*>(A + byte);
        }
#pragma unroll
        for (int g = 0; g < 4; ++g) {
            int chunk = (g * 8 + ks) * 16 + jf_global;
            short8 b = *reinterpret_cast<const short8*>(
                           Bp + ((size_t)chunk * 64 + lane) * 8);   // 1KB, contig
            acc[g][0] = __builtin_amdgcn_mfma_f32_16x16x32_bf16(cf[0], b, acc[g][0], 0, 0, 0);
            acc[g][1] = __builtin_amdgcn_mfma_f32_16x16x32_bf16(cf[1], b, acc[g][1], 0, 0, 0);
            acc[g][2] = __builtin_amdgcn_mfma_f32_16x16x32_bf16(cf[2], b, acc[g][2], 0, 0, 0);
            acc[g][3] = __builtin_amdgcn_mfma_f32_16x16x32_bf16(cf[3], b, acc[g][3], 0, 0, 0);
        }
    }

    // ---- cell loads AFTER GEMM (not live through K-loop) ------------------
    float* out0 = out;                               // out gate
    float* out1 = out + (size_t)Bsz * Hdim;          // hidden_state
    float* out2 = out + (size_t)2 * Bsz * Hdim;      // cell_state

#pragma unroll
    for (int mf = 0; mf < 4; ++mf) {
        float cv[4];
#pragma unroll
        for (int r = 0; r < 4; ++r)
            cv[r] = cell[(size_t)(rowblk + mf * 16 + lk * 4 + r) * Hdim + j];
#pragma unroll
        for (int r = 0; r < 4; ++r) {
            int row = rowblk + mf * 16 + lk * 4 + r;   // C/D: row=(lane>>4)*4+reg
            size_t off = (size_t)row * Hdim + j;
            float F = sigm(acc[0][mf][r]);
            float C = tanh_fast(acc[1][mf][r]);
            float I = sigm(sigm(acc[2][mf][r]));       // double sigmoid, per ref
            float O = sigm(acc[3][mf][r]);
            float cs = cv[r] * F + C * I;
            float hs = O * tanh_fast(cs);
            out0[off] = O;
            out1[off] = hs;
            out2[off] = cs;
        }
    }
}

extern "C" void kernel_launch(void* const* d_in, const int* in_sizes, int n_in,
                              void* d_out, int out_size, void* d_ws, size_t ws_size,
                              hipStream_t stream)
{
    const float* inp  = (const float*)d_in[0];
    const float* hid  = (const float*)d_in[1];
    const float* cell = (const float*)d_in[2];
    const float* Wf   = (const float*)d_in[3];
    const float* bf_  = (const float*)d_in[4];
    const float* Wc   = (const float*)d_in[5];
    const float* bc_  = (const float*)d_in[6];
    const float* Wi   = (const float*)d_in[7];
    const float* bi_  = (const float*)d_in[8];
    const float* Wo   = (const float*)d_in[9];
    const float* bo_  = (const float*)d_in[10];

    short* Bp = (short*)d_ws;    // 512 KB packed bf16 weights

    prep_w_kernel<<<1024, 256, 0, stream>>>(Wf, Wc, Wi, Wo, Bp);
    lstm_main<<<NBLK, 512, 0, stream>>>(inp, hid, cell, Bp,
                                        bf_, bc_, bi_, bo_, (float*)d_out);
}